// Round 9
// baseline (169.710 us; speedup 1.0000x reference)
//
#include <hip/hip_runtime.h>
#include <hip/hip_bf16.h>

// Problem: B=4096, L=50, D=64, E=128, CAT=384, U=256, V=100000
// Dtypes per reference: ALL float tensors fp32, ids/mask int32, out fp32 [B,E].
//
// Factored algebra: h = relu(q·W_q + k·W_k + (q*k)·W_qk + b_hide)
//   GEMM (swapped operands) C[u,l]: A-op = W fragments (global, coalesced),
//   B-op = [K | K*q] rows (LDS). C layout: col(lane&15)=l, row(quad*4+reg)=u.
//   qv[u] = q·W_q[:,u] via BROADCAST-B MFMA: B[k,l]=q[k] for all l -> every
//   lane's column holds qv[u] for its own u rows IN-REGISTER (accq). No LDS
//   round-trip, no extra barrier; + b_hide in epilogue (bit-identical to V7).
// scores = (relu(C+accq+b_hide)·W_out + b_out) * mask ; out[b] = scores·K
//
// History: V4 75.7 (W fragment coalescing, 2x). V5 112 REGRESSION (pipeline
// broke residency). V6 62.6 main but +22us prep. V7 68.0 main / 156.3 total
// (qv MFMA via planted row, but 2 extra barriers + LDS round-trip). V8 79.7
// REGRESSION (2 b's/block: 80KB LDS -> 2 blocks/CU, coarse 512-thr barriers;
// confirms many small 4-wave blocks win). V9 = V7 structure with: (1) qv via
// broadcast-q B-fragment, result in-lane (accq) -> deletes plant/qv_s/2
// barriers; (2) phases 1+2 fused (per-thread q from global, L1-broadcast)
// -> 1 barrier before MFMA. Barriers 6 -> 4; one 208-MFMA uninterrupted run.

#define L_SEQ 50
#define LP    64
#define D_EMB 64
#define E_DIM 128
#define U_DIM 256
#define V_SZ  100000
#define B_TOT 4096
#define KSTR  136   // LDS row stride (bf16): 272B = 17*16B -> bank rotation by 4/row

typedef __bf16 bf16x2 __attribute__((ext_vector_type(2)));
typedef __bf16 bf16x4 __attribute__((ext_vector_type(4)));
typedef __bf16 bf16x8 __attribute__((ext_vector_type(8)));
typedef float  f32x4  __attribute__((ext_vector_type(4)));

// module-owned: g_W3 = ALL of W_hide in MFMA fragment order, 12 K-slices:
// g_W3[((s*16+ut)*64+lane)*8+j] = bf16(W_hide[(s*32 + (lane>>4)*8 + j)*256
//                                            + ut*16 + (lane&15)])
// s=0..3 -> W_q (c 0..127), s=4..7 -> W_k, s=8..11 -> W_qk.  192 KB.
__device__ __bf16 g_W3[12288 * 8];

// ---- prep: g_W3 fragment shuffle (48 blocks x 256 thr, one fragment/thread) ----
__global__ __launch_bounds__(256) void prep_kernel(const float* __restrict__ W_hide) {
  const int o = blockIdx.x * 256 + threadIdx.x;   // 0..12287
  const int s = o >> 10, ut = (o >> 6) & 15, lane = o & 63;
  const int quad = lane >> 4, m = lane & 15;
  const int u = ut * 16 + m;
  const int c0 = s * 32 + quad * 8;
  bf16x8 v;
#pragma unroll
  for (int j = 0; j < 8; ++j)
    v[j] = (__bf16)W_hide[(c0 + j) * 256 + u];  // scattered 4B reads (tiny kernel)
  *(bf16x8*)&g_W3[o * 8] = v;                   // coalesced 16B write
}

// ---- main: one block (4 waves, 256 threads) per b ----
__global__ __launch_bounds__(256, 4) void din_main_kernel(
    const int* __restrict__ qid_item, const int* __restrict__ qid_cate,
    const int* __restrict__ seq_item, const int* __restrict__ seq_cate,
    const int* __restrict__ mask,
    const float* __restrict__ emb_item,
    const float* __restrict__ emb_cate,
    const float* __restrict__ b_hide,  // [256]
    const float* __restrict__ W_out,   // [256]
    const float* __restrict__ b_out,   // [1]
    float* __restrict__ out) {
  __shared__ alignas(16) __bf16 Kb[LP * KSTR];     // bf16(K)
  __shared__ alignas(16) __bf16 A2[LP * KSTR];     // bf16(K*q)
  __shared__ alignas(16) __bf16 qrow_h[E_DIM];     // bf16(q), 256 B
  __shared__ float mask_f[LP];
  __shared__ float scpart[4][LP];                  // per-wave u-partial scores
  __shared__ float scores_s[LP];
  __shared__ float outp[4][E_DIM];                 // per-wave l-partial outputs

  const int b = blockIdx.x;
  const int t = threadIdx.x;
  const int r = t >> 2, q4 = t & 3;
  const int col0 = q4 * 32;   // this thread's 32 columns of [item|cate]
  const int wave = t >> 6, lane = t & 63;
  const int m = lane & 15, quad = lane >> 4;

  // ---- phase A (fused 1+2): q slice (global, L1-broadcast), K gather,
  //      Kb + A2 + qrow_h + mask_f writes, ONE barrier. ----
  int qidv = (q4 < 2) ? qid_item[b] : qid_cate[b];
  if ((unsigned)qidv >= (unsigned)V_SZ) qidv = 0;
  const float4* qsrc = (const float4*)(((q4 < 2) ? emb_item : emb_cate)
                                       + (size_t)qidv * D_EMB + (q4 & 1) * 32);
  float4 qf[8];
#pragma unroll
  for (int i = 0; i < 8; ++i) qf[i] = qsrc[i];   // own 32 q cols (2-4 lines/instr)

  float4 kv[8];
  if (r < L_SEQ) {
    int id = (q4 < 2) ? seq_item[b * L_SEQ + r] : seq_cate[b * L_SEQ + r];
    if ((unsigned)id >= (unsigned)V_SZ) id = 0;   // insurance
    const float4* s4 = (const float4*)(((q4 < 2) ? emb_item : emb_cate)
                                       + (size_t)id * D_EMB + (q4 & 1) * 32);
#pragma unroll
    for (int i = 0; i < 8; ++i) kv[i] = s4[i];
  } else {
#pragma unroll
    for (int i = 0; i < 8; ++i) kv[i] = make_float4(0.f, 0.f, 0.f, 0.f);
  }
#pragma unroll
  for (int i = 0; i < 8; ++i) {
    bf16x4 h4 = {(__bf16)kv[i].x, (__bf16)kv[i].y, (__bf16)kv[i].z, (__bf16)kv[i].w};
    *(bf16x4*)&Kb[r * KSTR + col0 + i * 4] = h4;   // 8B store, aligned
    bf16x4 a4 = {(__bf16)(kv[i].x * qf[i].x), (__bf16)(kv[i].y * qf[i].y),
                 (__bf16)(kv[i].z * qf[i].z), (__bf16)(kv[i].w * qf[i].w)};
    *(bf16x4*)&A2[r * KSTR + col0 + i * 4] = a4;   // same rounding as V7
  }
  if (r == 0) {   // threads t=0..3 write their 32 cols of bf16(q)
#pragma unroll
    for (int i = 0; i < 8; ++i) {
      bf16x4 h4 = {(__bf16)qf[i].x, (__bf16)qf[i].y, (__bf16)qf[i].z, (__bf16)qf[i].w};
      *(bf16x4*)&qrow_h[col0 + i * 4] = h4;
    }
  }
  if (t < LP) mask_f[t] = (t < L_SEQ && mask[b * L_SEQ + t] != 0) ? 1.0f : 0.0f;
  __syncthreads();

  // ---- phase B: one uninterrupted MFMA run.
  //      accq first (slices 0..3, broadcast-q B): every column = qv[u], so each
  //      lane holds qv for its own u rows (quad*4+rg) -- no LDS, no barrier.
  f32x4 accq[4];
#pragma unroll
  for (int mt = 0; mt < 4; ++mt) accq[mt] = (f32x4){0.f, 0.f, 0.f, 0.f};
#pragma unroll
  for (int s = 0; s < 4; ++s) {
    const int klocal = s * 32 + quad * 8;
    bf16x8 kq = *(const bf16x8*)&qrow_h[klocal];   // uniform per quad: broadcast
    bf16x8 wq[4];
#pragma unroll
    for (int mt = 0; mt < 4; ++mt)
      wq[mt] = *(const bf16x8*)&g_W3[(s * 1024 + (wave * 4 + mt) * 64 + lane) * 8];
#pragma unroll
    for (int mt = 0; mt < 4; ++mt)
      accq[mt] = __builtin_amdgcn_mfma_f32_16x16x32_bf16(wq[mt], kq, accq[mt],
                                                         0, 0, 0);
  }

  //      main GEMM: M=u (64/wave, 4 tiles), N=l (64, 4 tiles), K=256
  //      (slices 4..11). A-op = g_W3 fragments, B-op = Kb/A2 rows (LDS).
  f32x4 acc[4][4];
#pragma unroll
  for (int mt = 0; mt < 4; ++mt)
#pragma unroll
    for (int nt = 0; nt < 4; ++nt) acc[mt][nt] = (f32x4){0.f, 0.f, 0.f, 0.f};

#pragma unroll
  for (int s = 0; s < 8; ++s) {
    const __bf16* Bb = (s < 4) ? Kb : A2;
    const int klocal = (s & 3) * 32 + quad * 8;
    bf16x8 wfr[4], kfr[4];
#pragma unroll
    for (int mt = 0; mt < 4; ++mt) {
      const int o = (4 + s) * 1024 + (wave * 4 + mt) * 64 + lane;  // frag-ordered
      wfr[mt] = *(const bf16x8*)&g_W3[o * 8];
    }
#pragma unroll
    for (int nt = 0; nt < 4; ++nt)
      kfr[nt] = *(const bf16x8*)&Bb[(nt * 16 + m) * KSTR + klocal];
#pragma unroll
    for (int mt = 0; mt < 4; ++mt)
#pragma unroll
      for (int nt = 0; nt < 4; ++nt)
        acc[mt][nt] = __builtin_amdgcn_mfma_f32_16x16x32_bf16(
            wfr[mt], kfr[nt], acc[mt][nt], 0, 0, 0);
  }
  // no barrier: epilogue reads only private acc/accq + global b_hide/W_out

  // ---- epilogue: C[u,l]: u = wave*64+mt*16+quad*4+rg (in-lane), l = nt*16+m.
  //      qv4 = accq + b_hide (same order as V7's 3a) ; part[nt] = relu-dot.
  float qv4[4][4], wo4[4][4];
#pragma unroll
  for (int mt = 0; mt < 4; ++mt) {
    const int u0 = wave * 64 + mt * 16 + quad * 4;
    float4 bh = *(const float4*)&b_hide[u0];
    float4 ww = *(const float4*)&W_out[u0];
    qv4[mt][0] = accq[mt][0] + bh.x; qv4[mt][1] = accq[mt][1] + bh.y;
    qv4[mt][2] = accq[mt][2] + bh.z; qv4[mt][3] = accq[mt][3] + bh.w;
    wo4[mt][0] = ww.x;  wo4[mt][1] = ww.y;  wo4[mt][2] = ww.z;  wo4[mt][3] = ww.w;
  }
  float part[4];
#pragma unroll
  for (int nt = 0; nt < 4; ++nt) {
    float sum = 0.f;
#pragma unroll
    for (int mt = 0; mt < 4; ++mt)
#pragma unroll
      for (int rg = 0; rg < 4; ++rg) {
        float h = acc[mt][nt][rg] + qv4[mt][rg];
        h = fmaxf(h, 0.f);
        sum += h * wo4[mt][rg];
      }
    part[nt] = sum;
  }
#pragma unroll
  for (int nt = 0; nt < 4; ++nt) {   // reduce over 4 quads
    part[nt] += __shfl_xor(part[nt], 16, 64);
    part[nt] += __shfl_xor(part[nt], 32, 64);
  }
  if (lane < 16) {
#pragma unroll
    for (int nt = 0; nt < 4; ++nt)
      scpart[wave][nt * 16 + lane] = part[nt];   // l = nt*16+lane
  }
  __syncthreads();

  // ---- scores (t<64), then wave-parallel out partials ----
  if (t < LP) {
    float s = scpart[0][t] + scpart[1][t] + scpart[2][t] + scpart[3][t]
            + b_out[0];
    scores_s[t] = s * mask_f[t];
  }
  __syncthreads();
  // wave w accumulates rows [w*16, w*16+16); lane covers e = 2*lane, 2*lane+1
  {
    const int e2 = lane * 2;
    float o0 = 0.f, o1 = 0.f;
#pragma unroll
    for (int i = 0; i < 16; ++i) {
      const int l = wave * 16 + i;
      const float sc = scores_s[l];                       // broadcast
      bf16x2 kk = *(const bf16x2*)&Kb[l * KSTR + e2];     // b32 pair, 2-way banks
      o0 += sc * (float)kk[0];
      o1 += sc * (float)kk[1];
    }
    outp[wave][e2]     = o0;
    outp[wave][e2 + 1] = o1;
  }
  __syncthreads();
  if (t < E_DIM) {
    float o = outp[0][t] + outp[1][t] + outp[2][t] + outp[3][t];
    out[(size_t)b * E_DIM + t] = o;
  }
}

extern "C" void kernel_launch(void* const* d_in, const int* in_sizes, int n_in,
                              void* d_out, int out_size, void* d_ws, size_t ws_size,
                              hipStream_t stream) {
  const int* qid_item = (const int*)d_in[0];
  const int* qid_cate = (const int*)d_in[1];
  const int* seq_item = (const int*)d_in[2];
  const int* seq_cate = (const int*)d_in[3];
  const int* mask     = (const int*)d_in[4];
  const float* emb_item = (const float*)d_in[5];
  const float* emb_cate = (const float*)d_in[6];
  const float* W_hide   = (const float*)d_in[7];
  const float* b_hide   = (const float*)d_in[8];
  const float* W_out    = (const float*)d_in[9];
  const float* b_out    = (const float*)d_in[10];
  float* out = (float*)d_out;

  (void)d_ws; (void)ws_size;  // intentionally unused

  prep_kernel<<<48, 256, 0, stream>>>(W_hide);
  din_main_kernel<<<B_TOT, 256, 0, stream>>>(qid_item, qid_cate, seq_item,
                                             seq_cate, mask, emb_item, emb_cate,
                                             b_hide, W_out, b_out, out);
}

// Round 10
// 164.112 us; speedup vs baseline: 1.0341x; 1.0341x over previous
//
#include <hip/hip_runtime.h>
#include <hip/hip_bf16.h>

// Problem: B=4096, L=50, D=64, E=128, CAT=384, U=256, V=100000
// Dtypes per reference: ALL float tensors fp32, ids/mask int32, out fp32 [B,E].
//
// Factored algebra: h = relu(q·W_q + k·W_k + (q*k)·W_qk + b_hide)
//   GEMM (swapped operands) C[u,l]: A-op = W fragments (global, coalesced),
//   B-op = [K | K*q] rows (LDS). C layout: col(lane&15)=l, row(quad*4+reg)=u.
//   qv[u] = b_hide[u] + q·W_q[:,u] via one N=16 MFMA tile (planted-q row 50,
//   garbage columns discarded); m==0 lanes stash qv in qv_s (LDS) so NO
//   accumulator is held across the main loop (V9's spill lesson).
// scores = (relu(C+qv)·W_out + b_out) * mask ; out[b] = scores · K   (fp32)
//
// History: V4 75.7 (W fragment coalescing, 2x). V5 112 REGR (pipeline broke
// residency). V6 62.6 main but +22us prep. V7 68.0 main / 156.3 total (best).
// V8 79.7 REGR (2 b/block: coarse barriers, 2 blocks/CU). V9 81.9 REGR:
// in-register qv (accq) held across main loop -> reg cap exceeded -> scratch
// spills (WRITE_SIZE 2->16.8MB, the smoking gun). V10 = V7 with two trims:
// (1) fused phase A (per-thread q from global, one barrier for Kb/A2/plant);
// (2) post-3a barrier DELETED: qv_s write (m==0, wave w) and epilogue read
// (same wave w) are same-wave LDS -> no __syncthreads needed. Barriers 6->4.
// Registers, MFMA count, rounding points: verbatim V7 -> absmax identical.

#define L_SEQ 50
#define LP    64
#define D_EMB 64
#define E_DIM 128
#define U_DIM 256
#define V_SZ  100000
#define B_TOT 4096
#define KSTR  136   // LDS row stride (bf16): 272B = 17*16B -> bank rotation by 4/row

typedef __bf16 bf16x2 __attribute__((ext_vector_type(2)));
typedef __bf16 bf16x4 __attribute__((ext_vector_type(4)));
typedef __bf16 bf16x8 __attribute__((ext_vector_type(8)));
typedef float  f32x4  __attribute__((ext_vector_type(4)));

// module-owned: g_W3 = ALL of W_hide in MFMA fragment order, 12 K-slices:
// g_W3[((s*16+ut)*64+lane)*8+j] = bf16(W_hide[(s*32 + (lane>>4)*8 + j)*256
//                                            + ut*16 + (lane&15)])
// s=0..3 -> W_q (c 0..127), s=4..7 -> W_k, s=8..11 -> W_qk.  192 KB.
__device__ __bf16 g_W3[12288 * 8];

// ---- prep: g_W3 fragment shuffle (48 blocks x 256 thr, one fragment/thread) ----
__global__ __launch_bounds__(256) void prep_kernel(const float* __restrict__ W_hide) {
  const int o = blockIdx.x * 256 + threadIdx.x;   // 0..12287
  const int s = o >> 10, ut = (o >> 6) & 15, lane = o & 63;
  const int quad = lane >> 4, m = lane & 15;
  const int u = ut * 16 + m;
  const int c0 = s * 32 + quad * 8;
  bf16x8 v;
#pragma unroll
  for (int j = 0; j < 8; ++j)
    v[j] = (__bf16)W_hide[(c0 + j) * 256 + u];  // scattered 4B reads (tiny kernel)
  *(bf16x8*)&g_W3[o * 8] = v;                   // coalesced 16B write
}

// ---- main: one block (4 waves, 256 threads) per b ----
__global__ __launch_bounds__(256, 4) void din_main_kernel(
    const int* __restrict__ qid_item, const int* __restrict__ qid_cate,
    const int* __restrict__ seq_item, const int* __restrict__ seq_cate,
    const int* __restrict__ mask,
    const float* __restrict__ emb_item,
    const float* __restrict__ emb_cate,
    const float* __restrict__ b_hide,  // [256]
    const float* __restrict__ W_out,   // [256]
    const float* __restrict__ b_out,   // [1]
    float* __restrict__ out) {
  // Kb and A2 CONTIGUOUS: qv B-fragment reads rows 50..65 of the combined array.
  __shared__ alignas(16) __bf16 KbA2[2 * LP * KSTR];   // 34816 B
  __shared__ alignas(16) float qv_s[U_DIM];            // b_hide + q·W_q (from MFMA)
  __shared__ float mask_f[LP];
  __shared__ float scpart[4][LP];                      // per-wave u-partial scores
  __shared__ float scores_s[LP];
  __shared__ float outp[4][E_DIM];                     // per-wave l-partial outputs
  __bf16* const Kb = KbA2;
  __bf16* const A2 = KbA2 + LP * KSTR;

  const int b = blockIdx.x;
  const int t = threadIdx.x;
  const int r = t >> 2, q4 = t & 3;
  const int col0 = q4 * 32;   // this thread's 32 columns of [item|cate]
  const int wave = t >> 6, lane = t & 63;
  const int m = lane & 15, quad = lane >> 4;

  // ---- phase A (fused): per-thread q slice (global, L1-broadcast), K gather,
  //      Kb + A2 + row-50 q plant + mask_f, ONE barrier. ----
  int qidv = (q4 < 2) ? qid_item[b] : qid_cate[b];
  if ((unsigned)qidv >= (unsigned)V_SZ) qidv = 0;
  const float4* qsrc = (const float4*)(((q4 < 2) ? emb_item : emb_cate)
                                       + (size_t)qidv * D_EMB + (q4 & 1) * 32);
  float4 qf[8];
#pragma unroll
  for (int i = 0; i < 8; ++i) qf[i] = qsrc[i];   // own 32 q cols (broadcast lines)

  float4 kv[8];
  if (r < L_SEQ) {
    int id = (q4 < 2) ? seq_item[b * L_SEQ + r] : seq_cate[b * L_SEQ + r];
    if ((unsigned)id >= (unsigned)V_SZ) id = 0;   // insurance
    const float4* s4 = (const float4*)(((q4 < 2) ? emb_item : emb_cate)
                                       + (size_t)id * D_EMB + (q4 & 1) * 32);
#pragma unroll
    for (int i = 0; i < 8; ++i) kv[i] = s4[i];
  } else {
#pragma unroll
    for (int i = 0; i < 8; ++i) kv[i] = make_float4(0.f, 0.f, 0.f, 0.f);
  }
#pragma unroll
  for (int i = 0; i < 8; ++i) {
    bf16x4 h4 = {(__bf16)kv[i].x, (__bf16)kv[i].y, (__bf16)kv[i].z, (__bf16)kv[i].w};
    *(bf16x4*)&Kb[r * KSTR + col0 + i * 4] = h4;   // 8B store, aligned
    bf16x4 a4 = {(__bf16)(kv[i].x * qf[i].x), (__bf16)(kv[i].y * qf[i].y),
                 (__bf16)(kv[i].z * qf[i].z), (__bf16)(kv[i].w * qf[i].w)};
    *(bf16x4*)&A2[r * KSTR + col0 + i * 4] = a4;   // same rounding as V7
  }
  if (r == 50) {   // plant bf16(q) into masked padding row 50 (after Kb write)
#pragma unroll
    for (int i = 0; i < 8; ++i) {
      bf16x4 h4 = {(__bf16)qf[i].x, (__bf16)qf[i].y, (__bf16)qf[i].z, (__bf16)qf[i].w};
      *(bf16x4*)&Kb[50 * KSTR + col0 + i * 4] = h4;
    }
  }
  if (t < LP) mask_f[t] = (t < L_SEQ && mask[b * L_SEQ + t] != 0) ? 1.0f : 0.0f;
  __syncthreads();

  // ---- phase 3a: qv via MFMA. One N=16 tile, K=128 (slices 0..3 = W_q).
  //      B rows = KbA2 rows 50..65: row 50 = q, rest zero/garbage (discarded).
  //      acc2 dies into qv_s immediately -> no regs held across main loop.
  {
    f32x4 acc2[4];
#pragma unroll
    for (int mt = 0; mt < 4; ++mt) acc2[mt] = (f32x4){0.f, 0.f, 0.f, 0.f};
#pragma unroll
    for (int s = 0; s < 4; ++s) {
      const int klocal = s * 32 + quad * 8;
      bf16x8 kq = *(const bf16x8*)&KbA2[(50 + m) * KSTR + klocal];
      bf16x8 wq[4];
#pragma unroll
      for (int mt = 0; mt < 4; ++mt)
        wq[mt] = *(const bf16x8*)&g_W3[(s * 1024 + (wave * 4 + mt) * 64 + lane) * 8];
#pragma unroll
      for (int mt = 0; mt < 4; ++mt)
        acc2[mt] = __builtin_amdgcn_mfma_f32_16x16x32_bf16(wq[mt], kq, acc2[mt],
                                                           0, 0, 0);
    }
    if (m == 0) {   // only column 0 (B-row 50 = q) is the true qv
#pragma unroll
      for (int mt = 0; mt < 4; ++mt) {
        const int u0 = wave * 64 + mt * 16 + quad * 4;
        float4 bh = *(const float4*)&b_hide[u0];
        f32x4 v = acc2[mt];
        v[0] += bh.x; v[1] += bh.y; v[2] += bh.z; v[3] += bh.w;
        *(f32x4*)&qv_s[u0] = v;
      }
    }
  }
  // NO barrier: qv_s written by m==0 lanes of wave w, read in epilogue ONLY by
  // lanes of the same wave w (u0 = wave*64+...). Same-wave LDS write->read is
  // ordered (DS pipe in-order per wave; compiler can't hoist aliasing load).

  // ---- phase 3b: main MFMA. M=u (64/wave, 4 tiles), N=l (64, 4 tiles),
  //      K=256 (slices 4..11). A-op = g_W3 fragments, B-op = Kb/A2 (LDS). ----
  f32x4 acc[4][4];
#pragma unroll
  for (int mt = 0; mt < 4; ++mt)
#pragma unroll
    for (int nt = 0; nt < 4; ++nt) acc[mt][nt] = (f32x4){0.f, 0.f, 0.f, 0.f};

#pragma unroll
  for (int s = 0; s < 8; ++s) {
    const __bf16* Bb = (s < 4) ? Kb : A2;
    const int klocal = (s & 3) * 32 + quad * 8;
    bf16x8 wfr[4], kfr[4];
#pragma unroll
    for (int mt = 0; mt < 4; ++mt) {
      const int o = (4 + s) * 1024 + (wave * 4 + mt) * 64 + lane;  // frag-ordered
      wfr[mt] = *(const bf16x8*)&g_W3[o * 8];
    }
#pragma unroll
    for (int nt = 0; nt < 4; ++nt)
      kfr[nt] = *(const bf16x8*)&Bb[(nt * 16 + m) * KSTR + klocal];
#pragma unroll
    for (int mt = 0; mt < 4; ++mt)
#pragma unroll
      for (int nt = 0; nt < 4; ++nt)
        acc[mt][nt] = __builtin_amdgcn_mfma_f32_16x16x32_bf16(
            wfr[mt], kfr[nt], acc[mt][nt], 0, 0, 0);
  }

  // ---- epilogue: C[u,l]: u = wave*64+mt*16+quad*4+rg (in-lane), l = nt*16+m.
  //      part[nt] = sum_u relu(C+qv[u])*W_out[u]  — u-reduce in-lane + quads.
  float qv4[4][4], wo4[4][4];
#pragma unroll
  for (int mt = 0; mt < 4; ++mt) {
    const int u0 = wave * 64 + mt * 16 + quad * 4;
    f32x4 qq = *(const f32x4*)&qv_s[u0];        // same-wave LDS read (see above)
    float4 ww = *(const float4*)&W_out[u0];
    qv4[mt][0] = qq[0]; qv4[mt][1] = qq[1]; qv4[mt][2] = qq[2]; qv4[mt][3] = qq[3];
    wo4[mt][0] = ww.x;  wo4[mt][1] = ww.y;  wo4[mt][2] = ww.z;  wo4[mt][3] = ww.w;
  }
  float part[4];
#pragma unroll
  for (int nt = 0; nt < 4; ++nt) {
    float sum = 0.f;
#pragma unroll
    for (int mt = 0; mt < 4; ++mt)
#pragma unroll
      for (int rg = 0; rg < 4; ++rg) {
        float h = acc[mt][nt][rg] + qv4[mt][rg];
        h = fmaxf(h, 0.f);
        sum += h * wo4[mt][rg];
      }
    part[nt] = sum;
  }
#pragma unroll
  for (int nt = 0; nt < 4; ++nt) {   // reduce over 4 quads
    part[nt] += __shfl_xor(part[nt], 16, 64);
    part[nt] += __shfl_xor(part[nt], 32, 64);
  }
  if (lane < 16) {
#pragma unroll
    for (int nt = 0; nt < 4; ++nt)
      scpart[wave][nt * 16 + lane] = part[nt];   // l = nt*16+lane
  }
  __syncthreads();

  // ---- scores (t<64), then wave-parallel out partials ----
  if (t < LP) {
    float s = scpart[0][t] + scpart[1][t] + scpart[2][t] + scpart[3][t]
            + b_out[0];
    scores_s[t] = s * mask_f[t];
  }
  __syncthreads();
  // wave w accumulates rows [w*16, w*16+16); lane covers e = 2*lane, 2*lane+1
  {
    const int e2 = lane * 2;
    float o0 = 0.f, o1 = 0.f;
#pragma unroll
    for (int i = 0; i < 16; ++i) {
      const int l = wave * 16 + i;
      const float sc = scores_s[l];                       // broadcast
      bf16x2 kk = *(const bf16x2*)&Kb[l * KSTR + e2];     // b32 pair, 2-way banks
      o0 += sc * (float)kk[0];
      o1 += sc * (float)kk[1];
    }
    outp[wave][e2]     = o0;
    outp[wave][e2 + 1] = o1;
  }
  __syncthreads();
  if (t < E_DIM) {
    float o = outp[0][t] + outp[1][t] + outp[2][t] + outp[3][t];
    out[(size_t)b * E_DIM + t] = o;
  }
}

extern "C" void kernel_launch(void* const* d_in, const int* in_sizes, int n_in,
                              void* d_out, int out_size, void* d_ws, size_t ws_size,
                              hipStream_t stream) {
  const int* qid_item = (const int*)d_in[0];
  const int* qid_cate = (const int*)d_in[1];
  const int* seq_item = (const int*)d_in[2];
  const int* seq_cate = (const int*)d_in[3];
  const int* mask     = (const int*)d_in[4];
  const float* emb_item = (const float*)d_in[5];
  const float* emb_cate = (const float*)d_in[6];
  const float* W_hide   = (const float*)d_in[7];
  const float* b_hide   = (const float*)d_in[8];
  const float* W_out    = (const float*)d_in[9];
  const float* b_out    = (const float*)d_in[10];
  float* out = (float*)d_out;

  (void)d_ws; (void)ws_size;  // intentionally unused

  prep_kernel<<<48, 256, 0, stream>>>(W_hide);
  din_main_kernel<<<B_TOT, 256, 0, stream>>>(qid_item, qid_cate, seq_item,
                                             seq_cate, mask, emb_item, emb_cate,
                                             b_hide, W_out, b_out, out);
}

// Round 11
// 161.125 us; speedup vs baseline: 1.0533x; 1.0185x over previous
//
#include <hip/hip_runtime.h>
#include <hip/hip_bf16.h>

// Problem: B=4096, L=50, D=64, E=128, CAT=384, U=256, V=100000
// Dtypes per reference: ALL float tensors fp32, ids/mask int32, out fp32 [B,E].
//
// Factored algebra: h = relu(q·W_q + k·W_k + (q*k)·W_qk + b_hide)
//   ONE GEMM per b (swapped operands), K extended to 384:
//   C[u,l] = sum_s W_slice_s · B_slice_s  with B-slices:
//     s=0..3  (W_q):  BROADCAST-q fragments (B[k][l]=q[k] for all l) -> adds
//                     qv[u] uniformly to every column, inside acc. No extra
//                     accumulator (V9's spill), no separate phase (V7's 3a).
//     s=4..7  (W_k):  Kb rows (LDS)
//     s=8..11 (W_qk): A2 rows (LDS)
//   C layout: col(lane&15)=l, row(quad*4+reg)=u.
// scores = (relu(C + b_hide)·W_out + b_out) * mask ; out[b] = scores·K (fp32)
//
// History: V4 75.7 (W fragment coalescing, 2x). V5 112 REGR (pipeline broke
// residency). V6 62.6 main but +22us prep. V7 68.0 main / 156.3 total.
// V8 79.7 REGR (2 b/block). V9 81.9 REGR: separate in-reg qv accumulator
// spilled (WRITE 2->16.8MB). V10 77 main: spill fixed (WRITE=2MB) but slower
// than V7 — barrier-less qv_s and/or fused q-load suspect. V11: qv folded
// INTO the main accumulator via broadcast-q K-extension -> deletes qv phase,
// planted row, qv_s, and the contested barrier entirely; single 192-MFMA run;
// register pressure strictly below V9. +48 MFMA/wave on a 20%-busy pipe.

#define L_SEQ 50
#define LP    64
#define D_EMB 64
#define E_DIM 128
#define U_DIM 256
#define V_SZ  100000
#define B_TOT 4096
#define KSTR  136   // LDS row stride (bf16): 272B = 17*16B -> bank rotation by 4/row

typedef __bf16 bf16x2 __attribute__((ext_vector_type(2)));
typedef __bf16 bf16x4 __attribute__((ext_vector_type(4)));
typedef __bf16 bf16x8 __attribute__((ext_vector_type(8)));
typedef float  f32x4  __attribute__((ext_vector_type(4)));

// module-owned: g_W3 = ALL of W_hide in MFMA fragment order, 12 K-slices:
// g_W3[((s*16+ut)*64+lane)*8+j] = bf16(W_hide[(s*32 + (lane>>4)*8 + j)*256
//                                            + ut*16 + (lane&15)])
// s=0..3 -> W_q (c 0..127), s=4..7 -> W_k, s=8..11 -> W_qk.  192 KB.
__device__ __bf16 g_W3[12288 * 8];

// ---- prep: g_W3 fragment shuffle (48 blocks x 256 thr, one fragment/thread) ----
__global__ __launch_bounds__(256) void prep_kernel(const float* __restrict__ W_hide) {
  const int o = blockIdx.x * 256 + threadIdx.x;   // 0..12287
  const int s = o >> 10, ut = (o >> 6) & 15, lane = o & 63;
  const int quad = lane >> 4, m = lane & 15;
  const int u = ut * 16 + m;
  const int c0 = s * 32 + quad * 8;
  bf16x8 v;
#pragma unroll
  for (int j = 0; j < 8; ++j)
    v[j] = (__bf16)W_hide[(c0 + j) * 256 + u];  // scattered 4B reads (tiny kernel)
  *(bf16x8*)&g_W3[o * 8] = v;                   // coalesced 16B write
}

// ---- main: one block (4 waves, 256 threads) per b ----
__global__ __launch_bounds__(256, 4) void din_main_kernel(
    const int* __restrict__ qid_item, const int* __restrict__ qid_cate,
    const int* __restrict__ seq_item, const int* __restrict__ seq_cate,
    const int* __restrict__ mask,
    const float* __restrict__ emb_item,
    const float* __restrict__ emb_cate,
    const float* __restrict__ b_hide,  // [256]
    const float* __restrict__ W_out,   // [256]
    const float* __restrict__ b_out,   // [1]
    float* __restrict__ out) {
  __shared__ alignas(16) __bf16 Kb[LP * KSTR];     // bf16(K)
  __shared__ alignas(16) __bf16 A2[LP * KSTR];     // bf16(K*q)
  __shared__ alignas(16) __bf16 qrow_h[E_DIM];     // bf16(q), 256 B
  __shared__ float mask_f[LP];
  __shared__ float scpart[4][LP];                  // per-wave u-partial scores
  __shared__ float scores_s[LP];
  __shared__ float outp[4][E_DIM];                 // per-wave l-partial outputs

  const int b = blockIdx.x;
  const int t = threadIdx.x;
  const int r = t >> 2, q4 = t & 3;
  const int col0 = q4 * 32;   // this thread's 32 columns of [item|cate]
  const int wave = t >> 6, lane = t & 63;
  const int m = lane & 15, quad = lane >> 4;

  // ---- phase A (fused): per-thread q slice (global, L1-broadcast), K gather,
  //      Kb + A2 + qrow_h + mask_f, ONE barrier. ----
  int qidv = (q4 < 2) ? qid_item[b] : qid_cate[b];
  if ((unsigned)qidv >= (unsigned)V_SZ) qidv = 0;
  const float4* qsrc = (const float4*)(((q4 < 2) ? emb_item : emb_cate)
                                       + (size_t)qidv * D_EMB + (q4 & 1) * 32);
  float4 qf[8];
#pragma unroll
  for (int i = 0; i < 8; ++i) qf[i] = qsrc[i];   // own 32 q cols (broadcast lines)

  float4 kv[8];
  if (r < L_SEQ) {
    int id = (q4 < 2) ? seq_item[b * L_SEQ + r] : seq_cate[b * L_SEQ + r];
    if ((unsigned)id >= (unsigned)V_SZ) id = 0;   // insurance
    const float4* s4 = (const float4*)(((q4 < 2) ? emb_item : emb_cate)
                                       + (size_t)id * D_EMB + (q4 & 1) * 32);
#pragma unroll
    for (int i = 0; i < 8; ++i) kv[i] = s4[i];
  } else {
#pragma unroll
    for (int i = 0; i < 8; ++i) kv[i] = make_float4(0.f, 0.f, 0.f, 0.f);
  }
#pragma unroll
  for (int i = 0; i < 8; ++i) {
    bf16x4 h4 = {(__bf16)kv[i].x, (__bf16)kv[i].y, (__bf16)kv[i].z, (__bf16)kv[i].w};
    *(bf16x4*)&Kb[r * KSTR + col0 + i * 4] = h4;   // 8B store, aligned
    bf16x4 a4 = {(__bf16)(kv[i].x * qf[i].x), (__bf16)(kv[i].y * qf[i].y),
                 (__bf16)(kv[i].z * qf[i].z), (__bf16)(kv[i].w * qf[i].w)};
    *(bf16x4*)&A2[r * KSTR + col0 + i * 4] = a4;   // same rounding as V7/V10
  }
  if (r == 0) {   // threads t=0..3 write their 32 cols of bf16(q)
#pragma unroll
    for (int i = 0; i < 8; ++i) {
      bf16x4 h4 = {(__bf16)qf[i].x, (__bf16)qf[i].y, (__bf16)qf[i].z, (__bf16)qf[i].w};
      *(bf16x4*)&qrow_h[col0 + i * 4] = h4;
    }
  }
  if (t < LP) mask_f[t] = (t < L_SEQ && mask[b * L_SEQ + t] != 0) ? 1.0f : 0.0f;
  __syncthreads();

  // ---- phase B: ONE uninterrupted MFMA run, K=384 (12 slices).
  //      s=0..3: broadcast-q B (adds qv[u] to every column, inside acc).
  //      s=4..7: Kb rows. s=8..11: A2 rows. ----
  f32x4 acc[4][4];
#pragma unroll
  for (int mt = 0; mt < 4; ++mt)
#pragma unroll
    for (int nt = 0; nt < 4; ++nt) acc[mt][nt] = (f32x4){0.f, 0.f, 0.f, 0.f};

#pragma unroll
  for (int s = 0; s < 12; ++s) {
    const int klocal = (s & 3) * 32 + quad * 8;
    bf16x8 wfr[4], kfr[4];
#pragma unroll
    for (int mt = 0; mt < 4; ++mt) {
      const int o = s * 1024 + (wave * 4 + mt) * 64 + lane;   // frag-ordered
      wfr[mt] = *(const bf16x8*)&g_W3[o * 8];
    }
    if (s < 4) {
      bf16x8 kq = *(const bf16x8*)&qrow_h[klocal];   // uniform per quad: broadcast
#pragma unroll
      for (int nt = 0; nt < 4; ++nt) kfr[nt] = kq;
    } else {
      const __bf16* Bb = (s < 8) ? Kb : A2;
#pragma unroll
      for (int nt = 0; nt < 4; ++nt)
        kfr[nt] = *(const bf16x8*)&Bb[(nt * 16 + m) * KSTR + klocal];
    }
#pragma unroll
    for (int mt = 0; mt < 4; ++mt)
#pragma unroll
      for (int nt = 0; nt < 4; ++nt)
        acc[mt][nt] = __builtin_amdgcn_mfma_f32_16x16x32_bf16(
            wfr[mt], kfr[nt], acc[mt][nt], 0, 0, 0);
  }
  // no barrier: epilogue reads only private acc + global b_hide/W_out

  // ---- epilogue: C[u,l]: u = wave*64+mt*16+quad*4+rg (in-lane), l = nt*16+m.
  //      h = relu(C + b_hide[u]); part[nt] = h·W_out (u-reduce in-lane + quads).
  float bh4[4][4], wo4[4][4];
#pragma unroll
  for (int mt = 0; mt < 4; ++mt) {
    const int u0 = wave * 64 + mt * 16 + quad * 4;
    float4 bh = *(const float4*)&b_hide[u0];
    float4 ww = *(const float4*)&W_out[u0];
    bh4[mt][0] = bh.x; bh4[mt][1] = bh.y; bh4[mt][2] = bh.z; bh4[mt][3] = bh.w;
    wo4[mt][0] = ww.x; wo4[mt][1] = ww.y; wo4[mt][2] = ww.z; wo4[mt][3] = ww.w;
  }
  float part[4];
#pragma unroll
  for (int nt = 0; nt < 4; ++nt) {
    float sum = 0.f;
#pragma unroll
    for (int mt = 0; mt < 4; ++mt)
#pragma unroll
      for (int rg = 0; rg < 4; ++rg) {
        float h = acc[mt][nt][rg] + bh4[mt][rg];
        h = fmaxf(h, 0.f);
        sum += h * wo4[mt][rg];
      }
    part[nt] = sum;
  }
#pragma unroll
  for (int nt = 0; nt < 4; ++nt) {   // reduce over 4 quads
    part[nt] += __shfl_xor(part[nt], 16, 64);
    part[nt] += __shfl_xor(part[nt], 32, 64);
  }
  if (lane < 16) {
#pragma unroll
    for (int nt = 0; nt < 4; ++nt)
      scpart[wave][nt * 16 + lane] = part[nt];   // l = nt*16+lane
  }
  __syncthreads();

  // ---- scores (t<64), then wave-parallel out partials ----
  if (t < LP) {
    float s = scpart[0][t] + scpart[1][t] + scpart[2][t] + scpart[3][t]
            + b_out[0];
    scores_s[t] = s * mask_f[t];
  }
  __syncthreads();
  // wave w accumulates rows [w*16, w*16+16); lane covers e = 2*lane, 2*lane+1
  {
    const int e2 = lane * 2;
    float o0 = 0.f, o1 = 0.f;
#pragma unroll
    for (int i = 0; i < 16; ++i) {
      const int l = wave * 16 + i;
      const float sc = scores_s[l];                       // broadcast
      bf16x2 kk = *(const bf16x2*)&Kb[l * KSTR + e2];     // b32 pair, 2-way banks
      o0 += sc * (float)kk[0];
      o1 += sc * (float)kk[1];
    }
    outp[wave][e2]     = o0;
    outp[wave][e2 + 1] = o1;
  }
  __syncthreads();
  if (t < E_DIM) {
    float o = outp[0][t] + outp[1][t] + outp[2][t] + outp[3][t];
    out[(size_t)b * E_DIM + t] = o;
  }
}

extern "C" void kernel_launch(void* const* d_in, const int* in_sizes, int n_in,
                              void* d_out, int out_size, void* d_ws, size_t ws_size,
                              hipStream_t stream) {
  const int* qid_item = (const int*)d_in[0];
  const int* qid_cate = (const int*)d_in[1];
  const int* seq_item = (const int*)d_in[2];
  const int* seq_cate = (const int*)d_in[3];
  const int* mask     = (const int*)d_in[4];
  const float* emb_item = (const float*)d_in[5];
  const float* emb_cate = (const float*)d_in[6];
  const float* W_hide   = (const float*)d_in[7];
  const float* b_hide   = (const float*)d_in[8];
  const float* W_out    = (const float*)d_in[9];
  const float* b_out    = (const float*)d_in[10];
  float* out = (float*)d_out;

  (void)d_ws; (void)ws_size;  // intentionally unused

  prep_kernel<<<48, 256, 0, stream>>>(W_hide);
  din_main_kernel<<<B_TOT, 256, 0, stream>>>(qid_item, qid_cate, seq_item,
                                             seq_cate, mask, emb_item, emb_cate,
                                             b_hide, W_out, b_out, out);
}

// Round 12
// 154.835 us; speedup vs baseline: 1.0961x; 1.0406x over previous
//
#include <hip/hip_runtime.h>
#include <hip/hip_bf16.h>

// Problem: B=4096, L=50, D=64, E=128, CAT=384, U=256, V=100000
// Dtypes per reference: ALL float tensors fp32, ids/mask int32, out fp32 [B,E].
//
// Factored algebra: h = relu(q·W_q + k·W_k + (q*k)·W_qk + b_hide)
//   GEMM (swapped operands) C[u,l]: A-op = W fragments (global, coalesced),
//   B-op = [K | K*q] rows (LDS). C layout: col(lane&15)=l, row(quad*4+reg)=u.
//   qv[u] = b_hide[u] + q·W_q[:,u] via one N=16 MFMA tile (planted-q row 50,
//   garbage columns discarded); m==0 lanes stash qv in qv_s (LDS).
// scores = (relu(C+qv)·W_out + b_out) * mask ; out[b] = scores · K   (fp32)
//
// History: V4 75.7 (W fragment coalescing, 2x). V5 112 REGR (pipeline broke
// residency). V6 62.6 main but +22us prep. V7 68.0 main / 156.3 total (BEST).
// V8 79.7 REGR (2 b/block). V9 81.9 REGR (qv acc held across main loop ->
// scratch spill, WRITE 16.8MB). V10 77 / V11 78: both carried a FUSED phase A
// (per-thread redundant q-loads) -> ~9us TA overhead (TA cost ~ instrs x lanes,
// not bytes); qv placement itself immaterial (V10~V11). V10 did prove the
// barrier-less qv_s path is CORRECT (same-wave write->read, identical absmax).
// V12 = exact V7 + ONLY that barrier deletion (one pipeline drain removed;
// staging/rounding/registers verbatim V7).

#define L_SEQ 50
#define LP    64
#define D_EMB 64
#define E_DIM 128
#define U_DIM 256
#define V_SZ  100000
#define B_TOT 4096
#define KSTR  136   // LDS row stride (bf16): 272B = 17*16B -> bank rotation by 4/row

typedef __bf16 bf16x2 __attribute__((ext_vector_type(2)));
typedef __bf16 bf16x4 __attribute__((ext_vector_type(4)));
typedef __bf16 bf16x8 __attribute__((ext_vector_type(8)));
typedef float  f32x4  __attribute__((ext_vector_type(4)));

// module-owned: g_W3 = ALL of W_hide in MFMA fragment order, 12 K-slices:
// g_W3[((s*16+ut)*64+lane)*8+j] = bf16(W_hide[(s*32 + (lane>>4)*8 + j)*256
//                                            + ut*16 + (lane&15)])
// s=0..3 -> W_q (c 0..127), s=4..7 -> W_k, s=8..11 -> W_qk.  192 KB.
__device__ __bf16 g_W3[12288 * 8];

// ---- prep: g_W3 fragment shuffle (48 blocks x 256 thr, one fragment/thread) ----
__global__ __launch_bounds__(256) void prep_kernel(const float* __restrict__ W_hide) {
  const int o = blockIdx.x * 256 + threadIdx.x;   // 0..12287
  const int s = o >> 10, ut = (o >> 6) & 15, lane = o & 63;
  const int quad = lane >> 4, m = lane & 15;
  const int u = ut * 16 + m;
  const int c0 = s * 32 + quad * 8;
  bf16x8 v;
#pragma unroll
  for (int j = 0; j < 8; ++j)
    v[j] = (__bf16)W_hide[(c0 + j) * 256 + u];  // scattered 4B reads (tiny kernel)
  *(bf16x8*)&g_W3[o * 8] = v;                   // coalesced 16B write
}

// ---- main: one block (4 waves, 256 threads) per b ----
__global__ __launch_bounds__(256, 4) void din_main_kernel(
    const int* __restrict__ qid_item, const int* __restrict__ qid_cate,
    const int* __restrict__ seq_item, const int* __restrict__ seq_cate,
    const int* __restrict__ mask,
    const float* __restrict__ emb_item,
    const float* __restrict__ emb_cate,
    const float* __restrict__ b_hide,  // [256]
    const float* __restrict__ W_out,   // [256]
    const float* __restrict__ b_out,   // [1]
    float* __restrict__ out) {
  // Kb and A2 CONTIGUOUS: qv B-fragment reads rows 50..65 of the combined array.
  __shared__ alignas(16) __bf16 KbA2[2 * LP * KSTR];   // 34816 B
  __shared__ alignas(16) float qrowf[E_DIM];           // fp32 q
  __shared__ alignas(16) float qv_s[U_DIM];            // b_hide + q·W_q (from MFMA)
  __shared__ float mask_f[LP];
  __shared__ float scpart[4][LP];                      // per-wave u-partial scores
  __shared__ float scores_s[LP];
  __shared__ float outp[4][E_DIM];                     // per-wave l-partial outputs
  __bf16* const Kb = KbA2;
  __bf16* const A2 = KbA2 + LP * KSTR;

  const int b = blockIdx.x;
  const int t = threadIdx.x;
  const int r = t >> 2, q4 = t & 3;
  const int col0 = q4 * 32;   // this thread's 32 columns of [item|cate]
  const int wave = t >> 6, lane = t & 63;
  const int m = lane & 15, quad = lane >> 4;

  // ---- phase 1: gather K rows (fp32) into regs, cast to LDS bf16 ----
  float4 kv[8];
  if (r < L_SEQ) {
    int id = (q4 < 2) ? seq_item[b * L_SEQ + r] : seq_cate[b * L_SEQ + r];
    if ((unsigned)id >= (unsigned)V_SZ) id = 0;   // insurance
    const float4* s4 = (const float4*)(((q4 < 2) ? emb_item : emb_cate)
                                       + (size_t)id * D_EMB + (q4 & 1) * 32);
#pragma unroll
    for (int i = 0; i < 8; ++i) kv[i] = s4[i];
  } else {
#pragma unroll
    for (int i = 0; i < 8; ++i) kv[i] = make_float4(0.f, 0.f, 0.f, 0.f);
  }
#pragma unroll
  for (int i = 0; i < 8; ++i) {
    bf16x4 h4 = {(__bf16)kv[i].x, (__bf16)kv[i].y, (__bf16)kv[i].z, (__bf16)kv[i].w};
    *(bf16x4*)&Kb[r * KSTR + col0 + i * 4] = h4;   // 8B store, aligned
  }
  if (t < 4) {   // q row: 4 threads x 32 floats
    int id = (t < 2) ? qid_item[b] : qid_cate[b];
    if ((unsigned)id >= (unsigned)V_SZ) id = 0;
    const float4* s4 = (const float4*)(((t < 2) ? emb_item : emb_cate)
                                       + (size_t)id * D_EMB + (t & 1) * 32);
    float4* d4 = (float4*)&qrowf[t * 32];
#pragma unroll
    for (int i = 0; i < 8; ++i) d4[i] = s4[i];
  }
  if (t < LP) mask_f[t] = (t < L_SEQ && mask[b * L_SEQ + t] != 0) ? 1.0f : 0.0f;
  __syncthreads();

  // ---- phase 2: A2 = bf16(K * q) from fp32 regs (single rounding);
  //      plant bf16(q) into Kb padding row 50 (masked row -> harmless) ----
#pragma unroll
  for (int i = 0; i < 8; ++i) {
    const float* qp = &qrowf[col0 + i * 4];
    bf16x4 h4 = {(__bf16)(kv[i].x * qp[0]), (__bf16)(kv[i].y * qp[1]),
                 (__bf16)(kv[i].z * qp[2]), (__bf16)(kv[i].w * qp[3])};
    *(bf16x4*)&A2[r * KSTR + col0 + i * 4] = h4;
  }
  if (r == 50) {
#pragma unroll
    for (int i = 0; i < 8; ++i) {
      const float* qp = &qrowf[col0 + i * 4];
      bf16x4 h4 = {(__bf16)qp[0], (__bf16)qp[1], (__bf16)qp[2], (__bf16)qp[3]};
      *(bf16x4*)&Kb[50 * KSTR + col0 + i * 4] = h4;
    }
  }
  __syncthreads();

  // ---- phase 3a: qv via MFMA. One N=16 tile, K=128 (slices 0..3 = W_q).
  //      B rows = KbA2 rows 50..65: row 50 = q, rest zero/garbage (discarded).
  {
    f32x4 acc2[4];
#pragma unroll
    for (int mt = 0; mt < 4; ++mt) acc2[mt] = (f32x4){0.f, 0.f, 0.f, 0.f};
#pragma unroll
    for (int s = 0; s < 4; ++s) {
      const int klocal = s * 32 + quad * 8;
      bf16x8 kq = *(const bf16x8*)&KbA2[(50 + m) * KSTR + klocal];
      bf16x8 wq[4];
#pragma unroll
      for (int mt = 0; mt < 4; ++mt)
        wq[mt] = *(const bf16x8*)&g_W3[(s * 1024 + (wave * 4 + mt) * 64 + lane) * 8];
#pragma unroll
      for (int mt = 0; mt < 4; ++mt)
        acc2[mt] = __builtin_amdgcn_mfma_f32_16x16x32_bf16(wq[mt], kq, acc2[mt],
                                                           0, 0, 0);
    }
    if (m == 0) {   // only column 0 (B-row 50 = q) is the true qv
#pragma unroll
      for (int mt = 0; mt < 4; ++mt) {
        const int u0 = wave * 64 + mt * 16 + quad * 4;
        float4 bh = *(const float4*)&b_hide[u0];
        f32x4 v = acc2[mt];
        v[0] += bh.x; v[1] += bh.y; v[2] += bh.z; v[3] += bh.w;
        *(f32x4*)&qv_s[u0] = v;
      }
    }
  }
  // NO barrier (V12's single change vs V7): qv_s written by m==0 lanes of wave
  // w, read in epilogue ONLY by lanes of the same wave w (u0 = wave*64+...).
  // Same-wave LDS write->read is ordered (in-order DS pipe; compiler cannot
  // hoist an aliasing load above the store). Correctness demonstrated in V10.

  // ---- phase 3b: main MFMA. M=u (64/wave, 4 tiles), N=l (64, 4 tiles),
  //      K=256 (slices 4..11). A-op = g_W3 fragments, B-op = Kb/A2 (LDS). ----
  f32x4 acc[4][4];
#pragma unroll
  for (int mt = 0; mt < 4; ++mt)
#pragma unroll
    for (int nt = 0; nt < 4; ++nt) acc[mt][nt] = (f32x4){0.f, 0.f, 0.f, 0.f};

#pragma unroll
  for (int s = 0; s < 8; ++s) {
    const __bf16* Bb = (s < 4) ? Kb : A2;
    const int klocal = (s & 3) * 32 + quad * 8;
    bf16x8 wfr[4], kfr[4];
#pragma unroll
    for (int mt = 0; mt < 4; ++mt) {
      const int o = (4 + s) * 1024 + (wave * 4 + mt) * 64 + lane;  // frag-ordered
      wfr[mt] = *(const bf16x8*)&g_W3[o * 8];
    }
#pragma unroll
    for (int nt = 0; nt < 4; ++nt)
      kfr[nt] = *(const bf16x8*)&Bb[(nt * 16 + m) * KSTR + klocal];
#pragma unroll
    for (int mt = 0; mt < 4; ++mt)
#pragma unroll
      for (int nt = 0; nt < 4; ++nt)
        acc[mt][nt] = __builtin_amdgcn_mfma_f32_16x16x32_bf16(
            wfr[mt], kfr[nt], acc[mt][nt], 0, 0, 0);
  }

  // ---- epilogue: C[u,l]: u = wave*64+mt*16+quad*4+rg (in-lane), l = nt*16+m.
  //      part[nt] = sum_u relu(C+qv[u])*W_out[u]  — u-reduce in-lane + quads.
  float qv4[4][4], wo4[4][4];
#pragma unroll
  for (int mt = 0; mt < 4; ++mt) {
    const int u0 = wave * 64 + mt * 16 + quad * 4;
    f32x4 qq = *(const f32x4*)&qv_s[u0];        // same-wave LDS read (see above)
    float4 ww = *(const float4*)&W_out[u0];
    qv4[mt][0] = qq[0]; qv4[mt][1] = qq[1]; qv4[mt][2] = qq[2]; qv4[mt][3] = qq[3];
    wo4[mt][0] = ww.x;  wo4[mt][1] = ww.y;  wo4[mt][2] = ww.z;  wo4[mt][3] = ww.w;
  }
  float part[4];
#pragma unroll
  for (int nt = 0; nt < 4; ++nt) {
    float sum = 0.f;
#pragma unroll
    for (int mt = 0; mt < 4; ++mt)
#pragma unroll
      for (int rg = 0; rg < 4; ++rg) {
        float h = acc[mt][nt][rg] + qv4[mt][rg];
        h = fmaxf(h, 0.f);
        sum += h * wo4[mt][rg];
      }
    part[nt] = sum;
  }
#pragma unroll
  for (int nt = 0; nt < 4; ++nt) {   // reduce over 4 quads
    part[nt] += __shfl_xor(part[nt], 16, 64);
    part[nt] += __shfl_xor(part[nt], 32, 64);
  }
  if (lane < 16) {
#pragma unroll
    for (int nt = 0; nt < 4; ++nt)
      scpart[wave][nt * 16 + lane] = part[nt];   // l = nt*16+lane
  }
  __syncthreads();

  // ---- scores (t<64), then wave-parallel out partials ----
  if (t < LP) {
    float s = scpart[0][t] + scpart[1][t] + scpart[2][t] + scpart[3][t]
            + b_out[0];
    scores_s[t] = s * mask_f[t];
  }
  __syncthreads();
  // wave w accumulates rows [w*16, w*16+16); lane covers e = 2*lane, 2*lane+1
  {
    const int e2 = lane * 2;
    float o0 = 0.f, o1 = 0.f;
#pragma unroll
    for (int i = 0; i < 16; ++i) {
      const int l = wave * 16 + i;
      const float sc = scores_s[l];                       // broadcast
      bf16x2 kk = *(const bf16x2*)&Kb[l * KSTR + e2];     // b32 pair, 2-way banks
      o0 += sc * (float)kk[0];
      o1 += sc * (float)kk[1];
    }
    outp[wave][e2]     = o0;
    outp[wave][e2 + 1] = o1;
  }
  __syncthreads();
  if (t < E_DIM) {
    float o = outp[0][t] + outp[1][t] + outp[2][t] + outp[3][t];
    out[(size_t)b * E_DIM + t] = o;
  }
}

extern "C" void kernel_launch(void* const* d_in, const int* in_sizes, int n_in,
                              void* d_out, int out_size, void* d_ws, size_t ws_size,
                              hipStream_t stream) {
  const int* qid_item = (const int*)d_in[0];
  const int* qid_cate = (const int*)d_in[1];
  const int* seq_item = (const int*)d_in[2];
  const int* seq_cate = (const int*)d_in[3];
  const int* mask     = (const int*)d_in[4];
  const float* emb_item = (const float*)d_in[5];
  const float* emb_cate = (const float*)d_in[6];
  const float* W_hide   = (const float*)d_in[7];
  const float* b_hide   = (const float*)d_in[8];
  const float* W_out    = (const float*)d_in[9];
  const float* b_out    = (const float*)d_in[10];
  float* out = (float*)d_out;

  (void)d_ws; (void)ws_size;  // intentionally unused

  prep_kernel<<<48, 256, 0, stream>>>(W_hide);
  din_main_kernel<<<B_TOT, 256, 0, stream>>>(qid_item, qid_cate, seq_item,
                                             seq_cate, mask, emb_item, emb_cate,
                                             b_hide, W_out, b_out, out);
}